// Round 1
// baseline (343.796 us; speedup 1.0000x reference)
//
#include <hip/hip_runtime.h>
#include <hip/hip_bf16.h>

typedef __attribute__((ext_vector_type(8))) short short8;
typedef __attribute__((ext_vector_type(4))) float f32x4;

__device__ __forceinline__ short f2bf(float f) {
    union { float f; unsigned u; } v; v.f = f;
    unsigned r = (v.u + 0x7fffu + ((v.u >> 16) & 1u)) >> 16;
    return (short)r;
}
__device__ __forceinline__ float bf2f(short s) {
    union { unsigned u; float f; } v; v.u = ((unsigned)(unsigned short)s) << 16;
    return v.f;
}
__device__ __forceinline__ f32x4 zero4() { f32x4 z = {0.f, 0.f, 0.f, 0.f}; return z; }

// ---------------------------------------------------------------------------
// Generic C[M,N] = A[M,K] @ B[N,K]^T  (both row-major, K contiguous).
// BM=BN=128, BK=32. 256 threads = 4 waves in 2x2, each wave 64x64 (4x4 MFMA).
// A is fp32 or bf16(short); B always fp32. Output fp32 or bf16.
// All shapes here are exact multiples of the tile sizes -> no bounds checks.
// ---------------------------------------------------------------------------
template<typename TA, bool STORE_BF16>
__device__ __forceinline__ void gemm_bt_core(
    const TA* __restrict__ A, const float* __restrict__ Bw, void* __restrict__ Cp,
    int K, int lda, int ldb, int ldc)
{
    __shared__ short As[128 * 40];   // rows padded 32->40 shorts (80B): 2-way bank alias only
    __shared__ short Bs[128 * 40];

    const int bm = blockIdx.y * 128;
    const int bn = blockIdx.x * 128;
    const int tid = threadIdx.x;
    const int w = tid >> 6;
    const int lane = tid & 63;
    const int l15 = lane & 15;
    const int quad = lane >> 4;
    const int wm = (w >> 1) * 64;
    const int wn = (w & 1) * 64;

    const int srow = tid >> 1;         // 0..127
    const int scol = (tid & 1) * 16;   // 0 or 16

    f32x4 acc[4][4];
#pragma unroll
    for (int i = 0; i < 4; i++)
#pragma unroll
        for (int j = 0; j < 4; j++) acc[i][j] = zero4();

    for (int k0 = 0; k0 < K; k0 += 32) {
        __syncthreads();
        // ---- stage A tile (128x32), convert to bf16 if needed ----
        {
            const TA* src = A + (size_t)(bm + srow) * lda + k0 + scol;
            short* dst = &As[srow * 40 + scol];
            if constexpr (sizeof(TA) == 4) {
                const float4* s4 = (const float4*)src;
                float4 f0 = s4[0], f1 = s4[1], f2 = s4[2], f3 = s4[3];
                short8 t0, t1;
                t0[0]=f2bf(f0.x); t0[1]=f2bf(f0.y); t0[2]=f2bf(f0.z); t0[3]=f2bf(f0.w);
                t0[4]=f2bf(f1.x); t0[5]=f2bf(f1.y); t0[6]=f2bf(f1.z); t0[7]=f2bf(f1.w);
                t1[0]=f2bf(f2.x); t1[1]=f2bf(f2.y); t1[2]=f2bf(f2.z); t1[3]=f2bf(f2.w);
                t1[4]=f2bf(f3.x); t1[5]=f2bf(f3.y); t1[6]=f2bf(f3.z); t1[7]=f2bf(f3.w);
                *(short8*)dst = t0; *(short8*)(dst + 8) = t1;
            } else {
                const uint4* s4 = (const uint4*)src;
                uint4 a = s4[0], b = s4[1];
                *(uint4*)dst = a; *(uint4*)(dst + 8) = b;
            }
        }
        // ---- stage B tile (128x32), fp32 -> bf16 ----
        {
            const float* src = Bw + (size_t)(bn + srow) * ldb + k0 + scol;
            short* dst = &Bs[srow * 40 + scol];
            const float4* s4 = (const float4*)src;
            float4 f0 = s4[0], f1 = s4[1], f2 = s4[2], f3 = s4[3];
            short8 t0, t1;
            t0[0]=f2bf(f0.x); t0[1]=f2bf(f0.y); t0[2]=f2bf(f0.z); t0[3]=f2bf(f0.w);
            t0[4]=f2bf(f1.x); t0[5]=f2bf(f1.y); t0[6]=f2bf(f1.z); t0[7]=f2bf(f1.w);
            t1[0]=f2bf(f2.x); t1[1]=f2bf(f2.y); t1[2]=f2bf(f2.z); t1[3]=f2bf(f2.w);
            t1[4]=f2bf(f3.x); t1[5]=f2bf(f3.y); t1[6]=f2bf(f3.z); t1[7]=f2bf(f3.w);
            *(short8*)dst = t0; *(short8*)(dst + 8) = t1;
        }
        __syncthreads();

        short8 af[4], bfr[4];
#pragma unroll
        for (int i = 0; i < 4; i++)
            af[i] = *(const short8*)&As[(wm + i * 16 + l15) * 40 + quad * 8];
#pragma unroll
        for (int j = 0; j < 4; j++)
            bfr[j] = *(const short8*)&Bs[(wn + j * 16 + l15) * 40 + quad * 8];
#pragma unroll
        for (int i = 0; i < 4; i++)
#pragma unroll
            for (int j = 0; j < 4; j++)
                acc[i][j] = __builtin_amdgcn_mfma_f32_16x16x32_bf16(af[i], bfr[j], acc[i][j], 0, 0, 0);
    }

    // ---- epilogue ----
#pragma unroll
    for (int i = 0; i < 4; i++)
#pragma unroll
        for (int j = 0; j < 4; j++) {
            int col = bn + wn + j * 16 + l15;
#pragma unroll
            for (int r = 0; r < 4; r++) {
                int row = bm + wm + i * 16 + quad * 4 + r;
                float v = acc[i][j][r];
                if constexpr (STORE_BF16)
                    ((short*)Cp)[(size_t)row * ldc + col] = f2bf(v);
                else
                    ((float*)Cp)[(size_t)row * ldc + col] = v;
            }
        }
}

// z=0: qh = q @ Wq[:512]^T; z=1: kh = k @ Wk[:512]^T; z=2: vmid = v[:,512:1024] @ Wv^T
__global__ __launch_bounds__(256) void proj_kernel(
    const float* __restrict__ q, const float* __restrict__ k, const float* __restrict__ v,
    const float* __restrict__ Wq, const float* __restrict__ Wk, const float* __restrict__ Wv,
    short* __restrict__ qh, short* __restrict__ kh, short* __restrict__ vmid)
{
    switch (blockIdx.z) {
    case 0:  gemm_bt_core<float, true>(q, Wq, qh, 1536, 1536, 1536, 512); break;
    case 1:  gemm_bt_core<float, true>(k, Wk, kh, 1536, 1536, 1536, 512); break;
    default: gemm_bt_core<float, true>(v + 512, Wv, vmid, 512, 1536, 512, 512); break;
    }
}

// out[4096,1536] = attn[4096,512] @ Wo[:, :512]^T  (attn cols 512.. are exactly 0)
__global__ __launch_bounds__(256) void outproj_kernel(
    const short* __restrict__ attn, const float* __restrict__ Wo, float* __restrict__ out)
{
    gemm_bt_core<short, false>(attn, Wo, out, 512, 512, 1536, 1536);
}

// Interleaved-pair RoPE, in place on bf16 [4096, 512]; position = row % 2048.
__global__ __launch_bounds__(256) void rope_kernel(short* __restrict__ qh, short* __restrict__ kh)
{
    short* buf = blockIdx.z ? kh : qh;
    int idx = blockIdx.x * 256 + threadIdx.x;
    int e0 = idx * 8;                 // 4 pairs
    int m = e0 >> 9;
    int c0 = e0 & 511;
    float pos = (float)(m & 2047);
    short8 xv = *(short8*)&buf[e0];
    short8 ov;
#pragma unroll
    for (int p = 0; p < 4; p++) {
        int col = c0 + 2 * p;
        int pair = (col & 127) >> 1;  // 0..63
        // freq = 10000^(-2*pair/128) = 2^(-(2*pair) * log2(10000)/128)
        float freq = exp2f(-(float)(2 * pair) * (13.287712379549449f / 128.0f));
        float ang = pos * freq;
        float s, c;
        __sincosf(ang, &s, &c);
        // accuracy: use precise versions
        s = sinf(ang); c = cosf(ang);
        float x1 = bf2f(xv[2 * p]), x2 = bf2f(xv[2 * p + 1]);
        ov[2 * p]     = f2bf(x1 * c - x2 * s);
        ov[2 * p + 1] = f2bf(x1 * s + x2 * c);
    }
    *(short8*)&buf[e0] = ov;
}

// ---------------------------------------------------------------------------
// Causal flash attention, 4 active heads, D=128, S=2048, B=2.
// Block = 256 thr (4 waves). Block handles (b, h, 64-row Q tile); wave w owns
// rows q0+16w..+15. KV tiles of 32 keys. Online softmax, fp32 state.
// ---------------------------------------------------------------------------
__global__ __launch_bounds__(256) void flash_kernel(
    const short* __restrict__ qh, const short* __restrict__ kh,
    const short* __restrict__ vmid, short* __restrict__ attn)
{
    __shared__ short Ks[32 * 136];    // [key][d], rows padded 128->136
    __shared__ short Vts[128 * 40];   // [d][key], rows padded 32->40
    __shared__ short Ps[4 * 16 * 40]; // per-wave P [16 q][32 key] padded ->40

    const int b = blockIdx.z;
    const int h = blockIdx.y;
    const int q0 = blockIdx.x * 64;
    const int tid = threadIdx.x;
    const int w = tid >> 6;
    const int lane = tid & 63;
    const int l15 = lane & 15;
    const int quad = lane >> 4;

    // Q fragments for this wave's 16 rows (kept in regs the whole kernel)
    const int rowq = q0 + w * 16 + l15;
    const size_t qoff = (size_t)(b * 2048 + rowq) * 512 + h * 128;
    short8 aq[4];
#pragma unroll
    for (int kk = 0; kk < 4; kk++)
        aq[kk] = *(const short8*)&qh[qoff + kk * 32 + quad * 8];

    f32x4 o[8];
#pragma unroll
    for (int dt = 0; dt < 8; dt++) o[dt] = zero4();
    float mrow[4], lrow[4];
#pragma unroll
    for (int r = 0; r < 4; r++) { mrow[r] = -1e30f; lrow[r] = 0.0f; }

    const float scale = 0.08838834764831845f; // 1/sqrt(128)
    const int ntiles = (q0 + 64) >> 5;

    const int skey = tid >> 3;        // 0..31
    const int sd0 = (tid & 7) * 16;   // 0,16,...,112

    for (int t = 0; t < ntiles; t++) {
        const int kbase = t * 32;
        __syncthreads();
        // ---- stage K[32][128] and V^T[128][32] ----
        {
            size_t goff = (size_t)(b * 2048 + kbase + skey) * 512 + h * 128 + sd0;
            uint4 kv0 = *(const uint4*)&kh[goff];
            uint4 kv1 = *(const uint4*)&kh[goff + 8];
            *(uint4*)&Ks[skey * 136 + sd0] = kv0;
            *(uint4*)&Ks[skey * 136 + sd0 + 8] = kv1;
            const short* vsrc = &vmid[goff];
#pragma unroll
            for (int j = 0; j < 16; j++)
                Vts[(sd0 + j) * 40 + skey] = vsrc[j];
        }
        __syncthreads();

        // ---- S = Q K^T (16q x 32k per wave) ----
        f32x4 sc[2];
#pragma unroll
        for (int ct = 0; ct < 2; ct++) {
            sc[ct] = zero4();
#pragma unroll
            for (int kk = 0; kk < 4; kk++) {
                short8 bk = *(const short8*)&Ks[(ct * 16 + l15) * 136 + kk * 32 + quad * 8];
                sc[ct] = __builtin_amdgcn_mfma_f32_16x16x32_bf16(aq[kk], bk, sc[ct], 0, 0, 0);
            }
        }

        // ---- scale + causal mask ----
        const int myrow = q0 + w * 16 + quad * 4;
        float s[2][4];
#pragma unroll
        for (int ct = 0; ct < 2; ct++) {
            int kcol = kbase + ct * 16 + l15;
#pragma unroll
            for (int r = 0; r < 4; r++) {
                float vv = sc[ct][r] * scale;
                s[ct][r] = (kcol > myrow + r) ? -1e30f : vv;
            }
        }

        // ---- online softmax (row reductions across the 16-lane group) ----
        float alpha[4];
#pragma unroll
        for (int r = 0; r < 4; r++) {
            float mx = fmaxf(s[0][r], s[1][r]);
#pragma unroll
            for (int off = 1; off < 16; off <<= 1)
                mx = fmaxf(mx, __shfl_xor(mx, off, 64));
            float mnew = fmaxf(mrow[r], mx);
            alpha[r] = __expf(mrow[r] - mnew);
            float psum = 0.f;
#pragma unroll
            for (int ct = 0; ct < 2; ct++) {
                float p = __expf(s[ct][r] - mnew);
                s[ct][r] = p;
                psum += p;
            }
#pragma unroll
            for (int off = 1; off < 16; off <<= 1)
                psum += __shfl_xor(psum, off, 64);
            lrow[r] = alpha[r] * lrow[r] + psum;
            mrow[r] = mnew;
#pragma unroll
            for (int dt = 0; dt < 8; dt++) o[dt][r] *= alpha[r];
        }

        // ---- P -> LDS (bf16, A-operand layout) ----
        short* pw = &Ps[w * 16 * 40];
#pragma unroll
        for (int ct = 0; ct < 2; ct++)
#pragma unroll
            for (int r = 0; r < 4; r++)
                pw[(quad * 4 + r) * 40 + ct * 16 + l15] = f2bf(s[ct][r]);
        __syncthreads();

        // ---- O += P V ----
        short8 ap = *(const short8*)&pw[l15 * 40 + quad * 8];
#pragma unroll
        for (int dt = 0; dt < 8; dt++) {
            short8 bv = *(const short8*)&Vts[(dt * 16 + l15) * 40 + quad * 8];
            o[dt] = __builtin_amdgcn_mfma_f32_16x16x32_bf16(ap, bv, o[dt], 0, 0, 0);
        }
    }

    // ---- epilogue: O / l -> attn bf16 ----
#pragma unroll
    for (int dt = 0; dt < 8; dt++)
#pragma unroll
        for (int r = 0; r < 4; r++) {
            int row = q0 + w * 16 + quad * 4 + r;
            float val = o[dt][r] / lrow[r];
            attn[(size_t)(b * 2048 + row) * 512 + h * 128 + dt * 16 + l15] = f2bf(val);
        }
}

extern "C" void kernel_launch(void* const* d_in, const int* in_sizes, int n_in,
                              void* d_out, int out_size, void* d_ws, size_t ws_size,
                              hipStream_t stream) {
    const float* q  = (const float*)d_in[0];
    const float* k  = (const float*)d_in[1];
    const float* v  = (const float*)d_in[2];
    const float* Wq = (const float*)d_in[3];
    const float* Wk = (const float*)d_in[4];
    const float* Wv = (const float*)d_in[5];
    const float* Wo = (const float*)d_in[6];
    float* out = (float*)d_out;

    char* ws = (char*)d_ws;
    short* qh   = (short*)(ws);                      // [4096,512] bf16 = 4MB
    short* kh   = (short*)(ws + 4u  * 1024 * 1024);  // 4MB
    short* vmid = (short*)(ws + 8u  * 1024 * 1024);  // 4MB
    short* attn = (short*)(ws + 12u * 1024 * 1024);  // 4MB

    // 1) projections (q, k, v-mid) — one launch, z selects which
    proj_kernel<<<dim3(4, 32, 3), 256, 0, stream>>>(q, k, v, Wq, Wk, Wv, qh, kh, vmid);
    // 2) RoPE on qh, kh
    rope_kernel<<<dim3(1024, 1, 2), 256, 0, stream>>>(qh, kh);
    // 3) causal flash attention over 4 active heads
    flash_kernel<<<dim3(32, 4, 2), 256, 0, stream>>>(qh, kh, vmid, attn);
    // 4) output projection (K=512 — attn heads 4..11 are exactly zero)
    outproj_kernel<<<dim3(12, 32, 1), 256, 0, stream>>>(attn, Wo, out);
}

// Round 3
// 315.710 us; speedup vs baseline: 1.0890x; 1.0890x over previous
//
#include <hip/hip_runtime.h>
#include <hip/hip_bf16.h>

typedef __attribute__((ext_vector_type(8))) short short8;
typedef __attribute__((ext_vector_type(4))) short short4v;
typedef __attribute__((ext_vector_type(4))) float f32x4;

__device__ __forceinline__ short f2bf(float f) {
    union { float f; unsigned u; } v; v.f = f;
    unsigned r = (v.u + 0x7fffu + ((v.u >> 16) & 1u)) >> 16;
    return (short)r;
}
__device__ __forceinline__ float bf2f(short s) {
    union { unsigned u; float f; } v; v.u = ((unsigned)(unsigned short)s) << 16;
    return v.f;
}
__device__ __forceinline__ f32x4 zero4() { f32x4 z = {0.f, 0.f, 0.f, 0.f}; return z; }

// ---------------------------------------------------------------------------
// C[M,N] = A[M,K] @ B[N,K]^T (row-major, K contiguous). BM=BN=128, BK=32.
// 256 thr = 4 waves in 2x2, each wave 64x64 (4x4 MFMA 16x16x32 bf16).
// A fp32 or bf16(short); B fp32 (converted in staging).
// STORE: 0 = bf16 row-major, 1 = bf16 TRANSPOSED (C^T[n][m]), 2 = fp32 row-major.
// Proven round-1 core; only the STORE=1 epilogue is new.
// ---------------------------------------------------------------------------
template<typename TA, int STORE>
__device__ __forceinline__ void gemm_bt_core(
    const TA* __restrict__ A, const float* __restrict__ Bw, void* __restrict__ Cp,
    int K, int lda, int ldb, int ldc)
{
    __shared__ short As[128 * 40];   // rows padded 32->40 shorts (80B)
    __shared__ short Bs[128 * 40];

    const int bm = blockIdx.y * 128;
    const int bn = blockIdx.x * 128;
    const int tid = threadIdx.x;
    const int w = tid >> 6;
    const int lane = tid & 63;
    const int l15 = lane & 15;
    const int quad = lane >> 4;
    const int wm = (w >> 1) * 64;
    const int wn = (w & 1) * 64;

    const int srow = tid >> 1;         // 0..127
    const int scol = (tid & 1) * 16;   // 0 or 16

    f32x4 acc[4][4];
#pragma unroll
    for (int i = 0; i < 4; i++)
#pragma unroll
        for (int j = 0; j < 4; j++) acc[i][j] = zero4();

    for (int k0 = 0; k0 < K; k0 += 32) {
        __syncthreads();
        {   // stage A tile (128x32)
            const TA* src = A + (size_t)(bm + srow) * lda + k0 + scol;
            short* dst = &As[srow * 40 + scol];
            if constexpr (sizeof(TA) == 4) {
                const float4* s4 = (const float4*)src;
                float4 f0 = s4[0], f1 = s4[1], f2 = s4[2], f3 = s4[3];
                short8 t0, t1;
                t0[0]=f2bf(f0.x); t0[1]=f2bf(f0.y); t0[2]=f2bf(f0.z); t0[3]=f2bf(f0.w);
                t0[4]=f2bf(f1.x); t0[5]=f2bf(f1.y); t0[6]=f2bf(f1.z); t0[7]=f2bf(f1.w);
                t1[0]=f2bf(f2.x); t1[1]=f2bf(f2.y); t1[2]=f2bf(f2.z); t1[3]=f2bf(f2.w);
                t1[4]=f2bf(f3.x); t1[5]=f2bf(f3.y); t1[6]=f2bf(f3.z); t1[7]=f2bf(f3.w);
                *(short8*)dst = t0; *(short8*)(dst + 8) = t1;
            } else {
                const uint4* s4 = (const uint4*)src;
                uint4 a = s4[0], b = s4[1];
                *(uint4*)dst = a; *(uint4*)(dst + 8) = b;
            }
        }
        {   // stage B tile (128x32), fp32 -> bf16
            const float* src = Bw + (size_t)(bn + srow) * ldb + k0 + scol;
            short* dst = &Bs[srow * 40 + scol];
            const float4* s4 = (const float4*)src;
            float4 f0 = s4[0], f1 = s4[1], f2 = s4[2], f3 = s4[3];
            short8 t0, t1;
            t0[0]=f2bf(f0.x); t0[1]=f2bf(f0.y); t0[2]=f2bf(f0.z); t0[3]=f2bf(f0.w);
            t0[4]=f2bf(f1.x); t0[5]=f2bf(f1.y); t0[6]=f2bf(f1.z); t0[7]=f2bf(f1.w);
            t1[0]=f2bf(f2.x); t1[1]=f2bf(f2.y); t1[2]=f2bf(f2.z); t1[3]=f2bf(f2.w);
            t1[4]=f2bf(f3.x); t1[5]=f2bf(f3.y); t1[6]=f2bf(f3.z); t1[7]=f2bf(f3.w);
            *(short8*)dst = t0; *(short8*)(dst + 8) = t1;
        }
        __syncthreads();

        short8 af[4], bfr[4];
#pragma unroll
        for (int i = 0; i < 4; i++)
            af[i] = *(const short8*)&As[(wm + i * 16 + l15) * 40 + quad * 8];
#pragma unroll
        for (int j = 0; j < 4; j++)
            bfr[j] = *(const short8*)&Bs[(wn + j * 16 + l15) * 40 + quad * 8];
#pragma unroll
        for (int i = 0; i < 4; i++)
#pragma unroll
            for (int j = 0; j < 4; j++)
                acc[i][j] = __builtin_amdgcn_mfma_f32_16x16x32_bf16(af[i], bfr[j], acc[i][j], 0, 0, 0);
    }

#pragma unroll
    for (int i = 0; i < 4; i++)
#pragma unroll
        for (int j = 0; j < 4; j++) {
            const int col = bn + wn + j * 16 + l15;
            const int row0 = bm + wm + i * 16 + quad * 4;
            if constexpr (STORE == 1) {
                short4v p;
#pragma unroll
                for (int r = 0; r < 4; r++) p[r] = f2bf(acc[i][j][r]);
                *(short4v*)&((short*)Cp)[(size_t)col * ldc + row0] = p;
            } else {
#pragma unroll
                for (int r = 0; r < 4; r++) {
                    if constexpr (STORE == 0)
                        ((short*)Cp)[(size_t)(row0 + r) * ldc + col] = f2bf(acc[i][j][r]);
                    else
                        ((float*)Cp)[(size_t)(row0 + r) * ldc + col] = acc[i][j][r];
                }
            }
        }
}

// z=0: qh = q@Wq[:512]^T [4096x512]; z=1: kh = k@Wk[:512]^T;
// z=2: vT = (v[:,512:1024]@Wv^T)^T stored [512x4096]
__global__ __launch_bounds__(256) void proj_kernel(
    const float* __restrict__ q, const float* __restrict__ k, const float* __restrict__ v,
    const float* __restrict__ Wq, const float* __restrict__ Wk, const float* __restrict__ Wv,
    short* __restrict__ qh, short* __restrict__ kh, short* __restrict__ vT)
{
    switch (blockIdx.z) {
    case 0:  gemm_bt_core<float, 0>(q, Wq, qh, 1536, 1536, 1536, 512); break;
    case 1:  gemm_bt_core<float, 0>(k, Wk, kh, 1536, 1536, 1536, 512); break;
    default: gemm_bt_core<float, 1>(v + 512, Wv, vT, 512, 1536, 512, 4096); break;
    }
}

// out[4096,1536] = attn[4096,512] @ Wo[:, :512]^T (fp32 out; attn heads 4..11 == 0)
__global__ __launch_bounds__(256) void outproj_kernel(
    const short* __restrict__ attn, const float* __restrict__ Wo, float* __restrict__ out)
{
    gemm_bt_core<short, 2>(attn, Wo, out, 512, 512, 1536, 1536);
}

// Interleaved-pair RoPE in place on bf16 [4096,512]; position = row % 2048.
// Exact-arithmetic range reduction, then fast sincos on |r| <= pi.
__global__ __launch_bounds__(256) void rope_kernel(short* __restrict__ qh, short* __restrict__ kh)
{
    short* buf = blockIdx.z ? kh : qh;
    const int idx = blockIdx.x * 256 + threadIdx.x;
    const int e0 = idx * 8;
    const int row = e0 >> 9;
    const int c0 = e0 & 511;
    const float pos = (float)(row & 2047);
    short8 xv = *(short8*)&buf[e0];
    short8 ov;
#pragma unroll
    for (int p = 0; p < 4; p++) {
        const int pair = ((c0 + 2 * p) & 127) >> 1;  // 0..63
        const float freq = exp2f(-(float)(2 * pair) * (13.287712379549449f / 128.0f));
        const float ang = pos * freq;                         // up to ~2047 rad
        const float n = rintf(ang * 0.15915494309189535f);    // nearest multiple of 2pi
        // 2pi = 6.28125 (exact to 9 bits) + 1.9353072e-3; n*hi exact for n<512
        const float r = (ang - n * 6.28125f) - n * 1.9353071795864769e-3f;
        float s, c;
        __sincosf(r, &s, &c);
        const float x1 = bf2f(xv[2 * p]), x2 = bf2f(xv[2 * p + 1]);
        ov[2 * p]     = f2bf(x1 * c - x2 * s);
        ov[2 * p + 1] = f2bf(x1 * s + x2 * c);
    }
    *(short8*)&buf[e0] = ov;
}

// ---------------------------------------------------------------------------
// Causal flash attention, KV-split across waves.
// Block = (b, h, 16-row Q tile), 4 waves; wave w takes KV tiles t==w (mod 4)
// with private online-softmax state; merge via LDS at the end.
// K and V^T fragments load straight from global (B-frag = 16B/lane contiguous).
// No __syncthreads in the KV loop.
// ---------------------------------------------------------------------------
__global__ __launch_bounds__(256) void flash_kernel(
    const short* __restrict__ qh, const short* __restrict__ kh,
    const short* __restrict__ vT, short* __restrict__ attn)
{
    __shared__ float Os[4][16][128];   // per-wave scaled O partials (32 KB)
    __shared__ short Ps[4][16 * 40];   // per-wave P scratch, padded to 40
    __shared__ float Ms[64], Lp[64];   // per-wave m / rescaled l (w*16+row)

    const int b = blockIdx.z;
    const int h = blockIdx.y;
    const int qt = 127 - blockIdx.x;   // heavy tiles first
    const int q0 = qt * 16;
    const int tid = threadIdx.x;
    const int w = tid >> 6;
    const int lane = tid & 63;
    const int l15 = lane & 15;
    const int quad = lane >> 4;

    const short* qrow = qh + (size_t)(b * 2048 + q0 + l15) * 512 + h * 128;
    short8 aq[4];
#pragma unroll
    for (int kk = 0; kk < 4; kk++)
        aq[kk] = *(const short8*)&qrow[kk * 32 + quad * 8];

    f32x4 o[8];
#pragma unroll
    for (int dt = 0; dt < 8; dt++) o[dt] = zero4();
    float mrow[4], lrow[4];
#pragma unroll
    for (int r = 0; r < 4; r++) { mrow[r] = -1e30f; lrow[r] = 0.0f; }

    const float scale = 0.08838834764831845f; // 1/sqrt(128)
    const int ntiles = (q0 + 47) >> 5;        // ceil((q0+16)/32)
    const short* kbp = kh + (size_t)(b * 2048) * 512 + h * 128;
    const short* vbp = vT + (size_t)(h * 128) * 4096 + b * 2048;
    short* pw = &Ps[w][0];

    for (int t = w; t < ntiles; t += 4) {
        const int kb0 = t * 32;

        // ---- S = Q K^T (16q x 32k) ----
        f32x4 sc[2];
#pragma unroll
        for (int ct = 0; ct < 2; ct++) {
            sc[ct] = zero4();
            const short* kr = kbp + (size_t)(kb0 + ct * 16 + l15) * 512;
#pragma unroll
            for (int kk = 0; kk < 4; kk++) {
                short8 bk = *(const short8*)&kr[kk * 32 + quad * 8];
                sc[ct] = __builtin_amdgcn_mfma_f32_16x16x32_bf16(aq[kk], bk, sc[ct], 0, 0, 0);
            }
        }

        // ---- scale + causal mask ----
        const int rbase = q0 + quad * 4;
        float s[2][4];
#pragma unroll
        for (int ct = 0; ct < 2; ct++) {
            const int kcol = kb0 + ct * 16 + l15;
#pragma unroll
            for (int r = 0; r < 4; r++) {
                float vv = sc[ct][r] * scale;
                s[ct][r] = (kcol > rbase + r) ? -1e30f : vv;
            }
        }

        // ---- online softmax (reduce across the 16-lane row group) ----
#pragma unroll
        for (int r = 0; r < 4; r++) {
            float mx = fmaxf(s[0][r], s[1][r]);
#pragma unroll
            for (int off = 1; off < 16; off <<= 1)
                mx = fmaxf(mx, __shfl_xor(mx, off, 64));
            const float mnew = fmaxf(mrow[r], mx);
            const float alpha = __expf(mrow[r] - mnew);
            float p0 = __expf(s[0][r] - mnew);
            float p1 = __expf(s[1][r] - mnew);
            s[0][r] = p0; s[1][r] = p1;
            float psum = p0 + p1;
#pragma unroll
            for (int off = 1; off < 16; off <<= 1)
                psum += __shfl_xor(psum, off, 64);
            lrow[r] = alpha * lrow[r] + psum;
            mrow[r] = mnew;
#pragma unroll
            for (int dt = 0; dt < 8; dt++) o[dt][r] *= alpha;
        }

        // ---- P -> per-wave LDS (A-operand layout); intra-wave, no barrier ----
#pragma unroll
        for (int ct = 0; ct < 2; ct++)
#pragma unroll
            for (int r = 0; r < 4; r++)
                pw[(quad * 4 + r) * 40 + ct * 16 + l15] = f2bf(s[ct][r]);
        short8 ap = *(const short8*)&pw[l15 * 40 + quad * 8];

        // ---- O += P V (V^T frags direct from global) ----
#pragma unroll
        for (int dt = 0; dt < 8; dt++) {
            short8 bv = *(const short8*)&vbp[(size_t)(dt * 16 + l15) * 4096 + kb0 + quad * 8];
            o[dt] = __builtin_amdgcn_mfma_f32_16x16x32_bf16(ap, bv, o[dt], 0, 0, 0);
        }
    }

    // ---- merge the 4 waves' online-softmax states ----
    if (l15 == 0) {
#pragma unroll
        for (int r = 0; r < 4; r++) Ms[w * 16 + quad * 4 + r] = mrow[r];
    }
    __syncthreads();
#pragma unroll
    for (int r = 0; r < 4; r++) {
        const int row = quad * 4 + r;
        float gm = fmaxf(fmaxf(Ms[row], Ms[16 + row]), fmaxf(Ms[32 + row], Ms[48 + row]));
        const float f = __expf(mrow[r] - gm);
        if (l15 == 0) Lp[w * 16 + row] = lrow[r] * f;
#pragma unroll
        for (int dt = 0; dt < 8; dt++)
            Os[w][row][dt * 16 + l15] = o[dt][r] * f;
    }
    __syncthreads();

    // ---- final reduce + store: thread t -> (row = t/16, 8 d-cols) ----
    {
        const int row = tid >> 4;
        const int d0 = (tid & 15) * 8;
        const float rL = 1.0f / (Lp[row] + Lp[16 + row] + Lp[32 + row] + Lp[48 + row]);
        short8 ov;
#pragma unroll
        for (int j = 0; j < 8; j++) {
            const float osum = Os[0][row][d0 + j] + Os[1][row][d0 + j]
                             + Os[2][row][d0 + j] + Os[3][row][d0 + j];
            ov[j] = f2bf(osum * rL);
        }
        *(short8*)&attn[(size_t)(b * 2048 + q0 + row) * 512 + h * 128 + d0] = ov;
    }
}

extern "C" void kernel_launch(void* const* d_in, const int* in_sizes, int n_in,
                              void* d_out, int out_size, void* d_ws, size_t ws_size,
                              hipStream_t stream) {
    const float* q  = (const float*)d_in[0];
    const float* k  = (const float*)d_in[1];
    const float* v  = (const float*)d_in[2];
    const float* Wq = (const float*)d_in[3];
    const float* Wk = (const float*)d_in[4];
    const float* Wv = (const float*)d_in[5];
    const float* Wo = (const float*)d_in[6];
    float* out = (float*)d_out;

    const size_t MB = 1024 * 1024;
    char* ws = (char*)d_ws;
    short* qh   = (short*)(ws);              // [4096,512] bf16, 4 MB
    short* kh   = (short*)(ws + 4 * MB);     // 4 MB
    short* vT   = (short*)(ws + 8 * MB);     // [512,4096], 4 MB
    short* attn = (short*)(ws + 12 * MB);    // [4096,512], 4 MB  (total 16 MB)

    proj_kernel<<<dim3(4, 32, 3), 256, 0, stream>>>(q, k, v, Wq, Wk, Wv, qh, kh, vT);
    rope_kernel<<<dim3(1024, 1, 2), 256, 0, stream>>>(qh, kh);
    flash_kernel<<<dim3(128, 4, 2), 256, 0, stream>>>(qh, kh, vT, attn);
    outproj_kernel<<<dim3(12, 32, 1), 256, 0, stream>>>(attn, Wo, out);
}

// Round 4
// 265.061 us; speedup vs baseline: 1.2970x; 1.1911x over previous
//
#include <hip/hip_runtime.h>
#include <hip/hip_bf16.h>

typedef __attribute__((ext_vector_type(8))) short short8;
typedef __attribute__((ext_vector_type(4))) short short4v;
typedef __attribute__((ext_vector_type(4))) float f32x4;

__device__ __forceinline__ short f2bf(float f) {
    union { float f; unsigned u; } v; v.f = f;
    unsigned r = (v.u + 0x7fffu + ((v.u >> 16) & 1u)) >> 16;
    return (short)r;
}
__device__ __forceinline__ float bf2f(short s) {
    union { unsigned u; float f; } v; v.u = ((unsigned)(unsigned short)s) << 16;
    return v.f;
}
__device__ __forceinline__ f32x4 zero4() { f32x4 z = {0.f, 0.f, 0.f, 0.f}; return z; }

// async global->LDS, 16B/lane; LDS dest = wave-uniform base, lane i lands at base+i*16
__device__ __forceinline__ void gl16(const void* g, void* l) {
    __builtin_amdgcn_global_load_lds(
        (const __attribute__((address_space(1))) void*)g,
        (__attribute__((address_space(3))) void*)l, 16, 0, 0);
}

// ---------------------------------------------------------------------------
// convertA: fp32 -> bf16 copies (before proj).
//  z=0: qb=q [4096x1536] -> d_out   z=1: kb=k -> d_out+12MB
//  z=2: Wqb=Wq[:512] [512x1536]     z=3: Wkb=Wk[:512]
// ---------------------------------------------------------------------------
__global__ __launch_bounds__(256) void convertA_kernel(
    const float* __restrict__ q, const float* __restrict__ k,
    const float* __restrict__ Wq, const float* __restrict__ Wk,
    short* __restrict__ qb, short* __restrict__ kb,
    short* __restrict__ Wqb, short* __restrict__ Wkb)
{
    const int e0 = (blockIdx.x * 256 + threadIdx.x) * 8;
    const float* src; short* dst; int n;
    switch (blockIdx.z) {
    case 0:  n = 6291456; src = q + e0;  dst = qb;  break;
    case 1:  n = 6291456; src = k + e0;  dst = kb;  break;
    case 2:  n = 786432;  src = Wq + e0; dst = Wqb; break;
    default: n = 786432;  src = Wk + e0; dst = Wkb; break;
    }
    if (e0 >= n) return;
    float4 f0 = ((const float4*)src)[0];
    float4 f1 = ((const float4*)src)[1];
    short8 o;
    o[0]=f2bf(f0.x); o[1]=f2bf(f0.y); o[2]=f2bf(f0.z); o[3]=f2bf(f0.w);
    o[4]=f2bf(f1.x); o[5]=f2bf(f1.y); o[6]=f2bf(f1.z); o[7]=f2bf(f1.w);
    *(short8*)(dst + e0) = o;
}

// convertB (after flash): Wob = Wo[:, :512] -> bf16 [1536x512]
__global__ __launch_bounds__(256) void convertB_kernel(
    const float* __restrict__ Wo, short* __restrict__ Wob)
{
    const int e0 = (blockIdx.x * 256 + threadIdx.x) * 8;   // < 786432
    const float* src = Wo + (size_t)(e0 >> 9) * 1536 + (e0 & 511);
    float4 f0 = ((const float4*)src)[0];
    float4 f1 = ((const float4*)src)[1];
    short8 o;
    o[0]=f2bf(f0.x); o[1]=f2bf(f0.y); o[2]=f2bf(f0.z); o[3]=f2bf(f0.w);
    o[4]=f2bf(f1.x); o[5]=f2bf(f1.y); o[6]=f2bf(f1.z); o[7]=f2bf(f1.w);
    *(short8*)(Wob + e0) = o;
}

// ---------------------------------------------------------------------------
// bf16 GEMM, m97 structure: C[M,N] = A[M,K] @ B[N,K]^T, 128x128xBK32 tiles,
// 4 waves 2x2, global_load_lds(16B) staging into unpadded [128][32] LDS.
// STORE: 0 = bf16 row-major, 2 = fp32 row-major.
// ---------------------------------------------------------------------------
template<int STORE>
__device__ __forceinline__ void gemm97(
    const short* __restrict__ A, const short* __restrict__ B, void* __restrict__ Cp,
    int K, int lda, int ldb, int ldc, short* As, short* Bs)
{
    const int bm = blockIdx.y * 128;
    const int bn = blockIdx.x * 128;
    const int tid = threadIdx.x;
    const int w = tid >> 6;
    const int lane = tid & 63;
    const int l15 = lane & 15;
    const int quad = lane >> 4;
    const int wm = (w >> 1) * 64;
    const int wn = (w & 1) * 64;

    // staging: wave w covers rows [w*32, w*32+32) in two 16-row gl16 calls
    const int srow = w * 32 + (lane >> 2);
    const int scol = (lane & 3) * 8;
    const short* ga = A + (size_t)(bm + srow) * lda + scol;
    const short* gb = B + (size_t)(bn + srow) * ldb + scol;
    short* laA0 = &As[(w * 32) * 32];
    short* laA1 = &As[(w * 32 + 16) * 32];
    short* laB0 = &Bs[(w * 32) * 32];
    short* laB1 = &Bs[(w * 32 + 16) * 32];

    f32x4 acc[4][4];
#pragma unroll
    for (int i = 0; i < 4; i++)
#pragma unroll
        for (int j = 0; j < 4; j++) acc[i][j] = zero4();

    for (int k0 = 0; k0 < K; k0 += 32) {
        __syncthreads();
        gl16(ga + k0, laA0);
        gl16(ga + k0 + (size_t)16 * lda, laA1);
        gl16(gb + k0, laB0);
        gl16(gb + k0 + (size_t)16 * ldb, laB1);
        __syncthreads();

        short8 af[4], bf[4];
#pragma unroll
        for (int i = 0; i < 4; i++)
            af[i] = *(const short8*)&As[(wm + i * 16 + l15) * 32 + quad * 8];
#pragma unroll
        for (int j = 0; j < 4; j++)
            bf[j] = *(const short8*)&Bs[(wn + j * 16 + l15) * 32 + quad * 8];
#pragma unroll
        for (int i = 0; i < 4; i++)
#pragma unroll
            for (int j = 0; j < 4; j++)
                acc[i][j] = __builtin_amdgcn_mfma_f32_16x16x32_bf16(af[i], bf[j], acc[i][j], 0, 0, 0);
    }

#pragma unroll
    for (int i = 0; i < 4; i++)
#pragma unroll
        for (int j = 0; j < 4; j++) {
            const int col = bn + wn + j * 16 + l15;
            const int row0 = bm + wm + i * 16 + quad * 4;
#pragma unroll
            for (int r = 0; r < 4; r++) {
                if constexpr (STORE == 0)
                    ((short*)Cp)[(size_t)(row0 + r) * ldc + col] = f2bf(acc[i][j][r]);
                else
                    ((float*)Cp)[(size_t)(row0 + r) * ldc + col] = acc[i][j][r];
            }
        }
}

// ---------------------------------------------------------------------------
// fp32-input GEMM (proven round-3 core): C = A @ B^T, fp32 staged+converted.
// STORE 1 = bf16 transposed (C^T[n][m]).
// ---------------------------------------------------------------------------
__device__ __forceinline__ void gemm_f32_bt_T(
    const float* __restrict__ A, const float* __restrict__ Bw, short* __restrict__ Cp,
    int K, int lda, int ldb, int ldc, short* As, short* Bs)
{
    const int bm = blockIdx.y * 128;
    const int bn = blockIdx.x * 128;
    const int tid = threadIdx.x;
    const int w = tid >> 6;
    const int lane = tid & 63;
    const int l15 = lane & 15;
    const int quad = lane >> 4;
    const int wm = (w >> 1) * 64;
    const int wn = (w & 1) * 64;
    const int srow = tid >> 1;
    const int scol = (tid & 1) * 16;

    f32x4 acc[4][4];
#pragma unroll
    for (int i = 0; i < 4; i++)
#pragma unroll
        for (int j = 0; j < 4; j++) acc[i][j] = zero4();

    for (int k0 = 0; k0 < K; k0 += 32) {
        __syncthreads();
        {
            const float* src = A + (size_t)(bm + srow) * lda + k0 + scol;
            short* dst = &As[srow * 40 + scol];
            const float4* s4 = (const float4*)src;
            float4 f0 = s4[0], f1 = s4[1], f2 = s4[2], f3 = s4[3];
            short8 t0, t1;
            t0[0]=f2bf(f0.x); t0[1]=f2bf(f0.y); t0[2]=f2bf(f0.z); t0[3]=f2bf(f0.w);
            t0[4]=f2bf(f1.x); t0[5]=f2bf(f1.y); t0[6]=f2bf(f1.z); t0[7]=f2bf(f1.w);
            t1[0]=f2bf(f2.x); t1[1]=f2bf(f2.y); t1[2]=f2bf(f2.z); t1[3]=f2bf(f2.w);
            t1[4]=f2bf(f3.x); t1[5]=f2bf(f3.y); t1[6]=f2bf(f3.z); t1[7]=f2bf(f3.w);
            *(short8*)dst = t0; *(short8*)(dst + 8) = t1;
        }
        {
            const float* src = Bw + (size_t)(bn + srow) * ldb + k0 + scol;
            short* dst = &Bs[srow * 40 + scol];
            const float4* s4 = (const float4*)src;
            float4 f0 = s4[0], f1 = s4[1], f2 = s4[2], f3 = s4[3];
            short8 t0, t1;
            t0[0]=f2bf(f0.x); t0[1]=f2bf(f0.y); t0[2]=f2bf(f0.z); t0[3]=f2bf(f0.w);
            t0[4]=f2bf(f1.x); t0[5]=f2bf(f1.y); t0[6]=f2bf(f1.z); t0[7]=f2bf(f1.w);
            t1[0]=f2bf(f2.x); t1[1]=f2bf(f2.y); t1[2]=f2bf(f2.z); t1[3]=f2bf(f2.w);
            t1[4]=f2bf(f3.x); t1[5]=f2bf(f3.y); t1[6]=f2bf(f3.z); t1[7]=f2bf(f3.w);
            *(short8*)dst = t0; *(short8*)(dst + 8) = t1;
        }
        __syncthreads();

        short8 af[4], bfr[4];
#pragma unroll
        for (int i = 0; i < 4; i++)
            af[i] = *(const short8*)&As[(wm + i * 16 + l15) * 40 + quad * 8];
#pragma unroll
        for (int j = 0; j < 4; j++)
            bfr[j] = *(const short8*)&Bs[(wn + j * 16 + l15) * 40 + quad * 8];
#pragma unroll
        for (int i = 0; i < 4; i++)
#pragma unroll
            for (int j = 0; j < 4; j++)
                acc[i][j] = __builtin_amdgcn_mfma_f32_16x16x32_bf16(af[i], bfr[j], acc[i][j], 0, 0, 0);
    }

#pragma unroll
    for (int i = 0; i < 4; i++)
#pragma unroll
        for (int j = 0; j < 4; j++) {
            const int col = bn + wn + j * 16 + l15;
            const int row0 = bm + wm + i * 16 + quad * 4;
            short4v p;
#pragma unroll
            for (int r = 0; r < 4; r++) p[r] = f2bf(acc[i][j][r]);
            *(short4v*)&Cp[(size_t)col * ldc + row0] = p;
        }
}

// z=0: qh = qb@Wqb^T; z=1: kh = kb@Wkb^T; z=2: vT = (v[:,512:1024]@Wv^T)^T
__global__ __launch_bounds__(256) void proj_kernel(
    const short* __restrict__ qb, const short* __restrict__ kb, const float* __restrict__ v,
    const short* __restrict__ Wqb, const short* __restrict__ Wkb, const float* __restrict__ Wv,
    short* __restrict__ qh, short* __restrict__ kh, short* __restrict__ vT)
{
    __shared__ short smem[2][5120];
    switch (blockIdx.z) {
    case 0:  gemm97<0>(qb, Wqb, qh, 1536, 1536, 1536, 512, smem[0], smem[1]); break;
    case 1:  gemm97<0>(kb, Wkb, kh, 1536, 1536, 1536, 512, smem[0], smem[1]); break;
    default: gemm_f32_bt_T(v + 512, Wv, vT, 512, 1536, 512, 4096, smem[0], smem[1]); break;
    }
}

// out[4096,1536] = attn[4096,512] @ Wob[1536,512]^T (fp32 out)
__global__ __launch_bounds__(256) void outproj_kernel(
    const short* __restrict__ attn, const short* __restrict__ Wob, float* __restrict__ out)
{
    __shared__ short smem[2][4096];
    gemm97<2>(attn, Wob, out, 512, 512, 512, 1536, smem[0], smem[1]);
}

// Interleaved-pair RoPE in place on bf16 [4096,512] (proven round-3 version).
__global__ __launch_bounds__(256) void rope_kernel(short* __restrict__ qh, short* __restrict__ kh)
{
    short* buf = blockIdx.z ? kh : qh;
    const int e0 = (blockIdx.x * 256 + threadIdx.x) * 8;
    const int row = e0 >> 9;
    const int c0 = e0 & 511;
    const float pos = (float)(row & 2047);
    short8 xv = *(short8*)&buf[e0];
    short8 ov;
#pragma unroll
    for (int p = 0; p < 4; p++) {
        const int pair = ((c0 + 2 * p) & 127) >> 1;
        const float freq = exp2f(-(float)(2 * pair) * (13.287712379549449f / 128.0f));
        const float ang = pos * freq;
        const float n = rintf(ang * 0.15915494309189535f);
        const float r = (ang - n * 6.28125f) - n * 1.9353071795864769e-3f;
        float s, c;
        __sincosf(r, &s, &c);
        const float x1 = bf2f(xv[2 * p]), x2 = bf2f(xv[2 * p + 1]);
        ov[2 * p]     = f2bf(x1 * c - x2 * s);
        ov[2 * p + 1] = f2bf(x1 * s + x2 * c);
    }
    *(short8*)&buf[e0] = ov;
}

// ---------------------------------------------------------------------------
// Causal flash attention, KV-split across waves, XCD-pinned (b,h).
// blockIdx.x (0..1023): id%8 -> (b,h) so each (b,h)'s 1MB K/V stays in one
// XCD's L2; id/8 -> q-tile (heavy first). V frags hoisted before softmax.
// ---------------------------------------------------------------------------
__global__ __launch_bounds__(256) void flash_kernel(
    const short* __restrict__ qh, const short* __restrict__ kh,
    const short* __restrict__ vT, short* __restrict__ attn)
{
    __shared__ float Os[4][16][128];
    __shared__ short Ps[4][16 * 40];
    __shared__ float Ms[64], Lp[64];

    const int id = blockIdx.x;
    const int hb = id & 7;
    const int b = hb & 1;
    const int h = hb >> 1;
    const int qt = 127 - (id >> 3);    // heavy tiles first
    const int q0 = qt * 16;
    const int tid = threadIdx.x;
    const int w = tid >> 6;
    const int lane = tid & 63;
    const int l15 = lane & 15;
    const int quad = lane >> 4;

    const short* qrow = qh + (size_t)(b * 2048 + q0 + l15) * 512 + h * 128;
    short8 aq[4];
#pragma unroll
    for (int kk = 0; kk < 4; kk++)
        aq[kk] = *(const short8*)&qrow[kk * 32 + quad * 8];

    f32x4 o[8];
#pragma unroll
    for (int dt = 0; dt < 8; dt++) o[dt] = zero4();
    float mrow[4], lrow[4];
#pragma unroll
    for (int r = 0; r < 4; r++) { mrow[r] = -1e30f; lrow[r] = 0.0f; }

    const float scale = 0.08838834764831845f;
    const int ntiles = (q0 + 47) >> 5;
    const short* kbp = kh + (size_t)(b * 2048) * 512 + h * 128;
    const short* vbp = vT + (size_t)(h * 128) * 4096 + b * 2048;
    short* pw = &Ps[w][0];

    for (int t = w; t < ntiles; t += 4) {
        const int kb0 = t * 32;

        // ---- S = Q K^T ----
        f32x4 sc[2];
#pragma unroll
        for (int ct = 0; ct < 2; ct++) {
            sc[ct] = zero4();
            const short* kr = kbp + (size_t)(kb0 + ct * 16 + l15) * 512;
#pragma unroll
            for (int kk = 0; kk < 4; kk++) {
                short8 bk = *(const short8*)&kr[kk * 32 + quad * 8];
                sc[ct] = __builtin_amdgcn_mfma_f32_16x16x32_bf16(aq[kk], bk, sc[ct], 0, 0, 0);
            }
        }

        // ---- hoist V-fragment loads: latency hides under softmax ----
        short8 bv[8];
#pragma unroll
        for (int dt = 0; dt < 8; dt++)
            bv[dt] = *(const short8*)&vbp[(size_t)(dt * 16 + l15) * 4096 + kb0 + quad * 8];

        // ---- scale + causal mask ----
        const int rbase = q0 + quad * 4;
        float s[2][4];
#pragma unroll
        for (int ct = 0; ct < 2; ct++) {
            const int kcol = kb0 + ct * 16 + l15;
#pragma unroll
            for (int r = 0; r < 4; r++) {
                float vv = sc[ct][r] * scale;
                s[ct][r] = (kcol > rbase + r) ? -1e30f : vv;
            }
        }

        // ---- online softmax ----
#pragma unroll
        for (int r = 0; r < 4; r++) {
            float mx = fmaxf(s[0][r], s[1][r]);
#pragma unroll
            for (int off = 1; off < 16; off <<= 1)
                mx = fmaxf(mx, __shfl_xor(mx, off, 64));
            const float mnew = fmaxf(mrow[r], mx);
            const float alpha = __expf(mrow[r] - mnew);
            float p0 = __expf(s[0][r] - mnew);
            float p1 = __expf(s[1][r] - mnew);
            s[0][r] = p0; s[1][r] = p1;
            float psum = p0 + p1;
#pragma unroll
            for (int off = 1; off < 16; off <<= 1)
                psum += __shfl_xor(psum, off, 64);
            lrow[r] = alpha * lrow[r] + psum;
            mrow[r] = mnew;
#pragma unroll
            for (int dt = 0; dt < 8; dt++) o[dt][r] *= alpha;
        }

        // ---- P -> per-wave LDS (A-layout), intra-wave ----
#pragma unroll
        for (int ct = 0; ct < 2; ct++)
#pragma unroll
            for (int r = 0; r < 4; r++)
                pw[(quad * 4 + r) * 40 + ct * 16 + l15] = f2bf(s[ct][r]);
        short8 ap = *(const short8*)&pw[l15 * 40 + quad * 8];

        // ---- O += P V ----
#pragma unroll
        for (int dt = 0; dt < 8; dt++)
            o[dt] = __builtin_amdgcn_mfma_f32_16x16x32_bf16(ap, bv[dt], o[dt], 0, 0, 0);
    }

    // ---- merge 4 waves' states ----
    if (l15 == 0) {
#pragma unroll
        for (int r = 0; r < 4; r++) Ms[w * 16 + quad * 4 + r] = mrow[r];
    }
    __syncthreads();
#pragma unroll
    for (int r = 0; r < 4; r++) {
        const int row = quad * 4 + r;
        float gm = fmaxf(fmaxf(Ms[row], Ms[16 + row]), fmaxf(Ms[32 + row], Ms[48 + row]));
        const float f = __expf(mrow[r] - gm);
        if (l15 == 0) Lp[w * 16 + row] = lrow[r] * f;
#pragma unroll
        for (int dt = 0; dt < 8; dt++)
            Os[w][row][dt * 16 + l15] = o[dt][r] * f;
    }
    __syncthreads();

    {
        const int row = tid >> 4;
        const int d0 = (tid & 15) * 8;
        const float rL = 1.0f / (Lp[row] + Lp[16 + row] + Lp[32 + row] + Lp[48 + row]);
        short8 ov;
#pragma unroll
        for (int j = 0; j < 8; j++) {
            const float osum = Os[0][row][d0 + j] + Os[1][row][d0 + j]
                             + Os[2][row][d0 + j] + Os[3][row][d0 + j];
            ov[j] = f2bf(osum * rL);
        }
        *(short8*)&attn[(size_t)(b * 2048 + q0 + row) * 512 + h * 128 + d0] = ov;
    }
}

extern "C" void kernel_launch(void* const* d_in, const int* in_sizes, int n_in,
                              void* d_out, int out_size, void* d_ws, size_t ws_size,
                              hipStream_t stream) {
    const float* q  = (const float*)d_in[0];
    const float* k  = (const float*)d_in[1];
    const float* v  = (const float*)d_in[2];
    const float* Wq = (const float*)d_in[3];
    const float* Wk = (const float*)d_in[4];
    const float* Wv = (const float*)d_in[5];
    const float* Wo = (const float*)d_in[6];
    float* out = (float*)d_out;

    const size_t MB = 1024 * 1024;
    // ws (16 MB total, proven size):
    char* ws = (char*)d_ws;
    short* qh   = (short*)(ws);               // [4096,512] bf16, 4 MB (dead after flash)
    short* kh   = (short*)(ws + 4 * MB);      // 4 MB
    short* vT   = (short*)(ws + 8 * MB);      // [512,4096], 4 MB
    short* Wqb  = (short*)(ws + 12 * MB);     // [512,1536] bf16, 1.5 MB (dead after proj)
    short* Wkb  = (short*)(ws + 13 * MB + 512 * 1024);  // 1.5 MB (dead after proj)
    short* attn = (short*)(ws + 12 * MB);     // [4096,512], 4 MB (written by flash, over Wqb/Wkb)
    short* Wob  = (short*)(ws);               // [1536,512] bf16, 1.5 MB (over dead qh)
    // d_out (24 MB) doubles as scratch for the bf16 activation copies until outproj:
    short* qb   = (short*)d_out;              // [4096,1536] bf16, 12 MB
    short* kb   = (short*)((char*)d_out + 12 * MB);  // 12 MB

    // 1) fp32 -> bf16 copies (q, k, Wq-slice, Wk-slice)
    convertA_kernel<<<dim3(3072, 1, 4), 256, 0, stream>>>(q, k, Wq, Wk, qb, kb, Wqb, Wkb);
    // 2) projections: qh/kh via bf16+gl16 GEMM; vT via proven fp32 core
    proj_kernel<<<dim3(4, 32, 3), 256, 0, stream>>>(qb, kb, v, Wqb, Wkb, Wv, qh, kh, vT);
    // 3) RoPE
    rope_kernel<<<dim3(1024, 1, 2), 256, 0, stream>>>(qh, kh);
    // 4) flash attention (XCD-pinned (b,h)); writes attn over dead Wqb/Wkb
    flash_kernel<<<dim3(1024, 1, 1), 256, 0, stream>>>(qh, kh, vT, attn);
    // 5) Wo slice -> bf16 into dead qh region
    convertB_kernel<<<dim3(384, 1, 1), 256, 0, stream>>>(Wo, Wob);
    // 6) output projection (bf16+gl16), overwrites d_out scratch with final result
    outproj_kernel<<<dim3(12, 32, 1), 256, 0, stream>>>(attn, Wob, out);
}